// Round 16
// baseline (728.997 us; speedup 1.0000x reference)
//
#include <hip/hip_runtime.h>
#include <stdint.h>

#define NVV 300000
#define NFF 1500000
#define NE  9000000
#define NGRID 1225
#define NB   262144        // key-space buckets = 2^18 (fine)
#define BSH  14            // fine bucket = skey >> BSH
#define BCAP 256           // LDS bucket capacity per wave (k3 fallback)
#define NC   512           // coarse bins
#define CSH  23            // coarse bin = skey >> CSH
#define NF2  512           // fine bins per coarse
#define NBLK1 2048         // blocks for kA/kB
#define NHIST (NC * NBLK1) // 1,048,576

// d_out layout (float32 element offsets)
#define OFF_VERTS 0
#define OFF_FACES 27000000
#define OFF_MASK  36000000
#define OFF_NTRI  39000000
#define OFF_CROSS 40500000
#define OFF_UVS   49500000
#define OFF_UVIDX 61505000

// ALL scratch lives in d_out; d_ws never used. Overlays (lifetime-disjoint):
//   dcnt  overlays gHist (dead after scan1's scan_add; kC writes dcnt)
//   base2 overlays gScan (dead after kC)
#define S_PAIR  49500000u                  // bPair: 9M uint2 = 18M u32 -> 67,500,000
#define S_GH    67500000u                  // gHist: NHIST    [later: dcnt]
#define S_GS    (S_GH + NHIST)             // gScan: NHIST    [later: base2]
#define S_OFF1  (S_GS + NHIST)             // NB+1
#define S_BSUMS (S_OFF1 + NB + 1)          // 1024
#define S_SSUMS (S_BSUMS + 1024)           // 1024
#define S_FLG   (S_SSUMS + 1024)           // 8
#define S_TI    (S_FLG + 8)                // 375,000 u32 -> ends < 70,505,000
// staging: 9M uint2 in the verts region (memset after kC)
// idx_map: 9M u32 in the faces region (k3 -> k5)

#define ENC3(x) ((unsigned)(((x) < 0) ? 7 : (x)))
#define PACK6(a,b,c,d,e,f) (ENC3(a) | (ENC3(b)<<3) | (ENC3(c)<<6) | \
                            (ENC3(d)<<9) | (ENC3(e)<<12) | (ENC3(f)<<15))
__constant__ unsigned TROW[16] = {
    PACK6(-1,-1,-1,-1,-1,-1), PACK6(1,0,2,-1,-1,-1), PACK6(4,0,3,-1,-1,-1), PACK6(1,4,2,1,3,4),
    PACK6(3,1,5,-1,-1,-1),    PACK6(2,3,0,2,5,3),    PACK6(1,4,0,1,5,4),    PACK6(4,2,5,-1,-1,-1),
    PACK6(4,5,2,-1,-1,-1),    PACK6(4,1,0,4,5,1),    PACK6(3,2,0,3,5,2),    PACK6(1,3,5,-1,-1,-1),
    PACK6(4,1,2,4,3,1),       PACK6(3,0,4,-1,-1,-1), PACK6(2,0,1,-1,-1,-1), PACK6(-1,-1,-1,-1,-1,-1)};

__device__ __forceinline__ int tidx(const float* sdf, int v0, int v1, int v2, int v3) {
    int ti = 0;
    if (sdf[v0] > 0.0f) ti |= 1;
    if (sdf[v1] > 0.0f) ti |= 2;
    if (sdf[v2] > 0.0f) ti |= 4;
    if (sdf[v3] > 0.0f) ti |= 8;
    return ti;
}

__device__ __forceinline__ unsigned skey_of(int a, int b) {
    int ea = a < b ? a : b;
    int eb = a < b ? b : a;
    unsigned ukey = (unsigned)ea * 300000u + (unsigned)eb;   // wraps like int32
    return ukey ^ 0x80000000u;
}

// full-wave bitonic sort of packed (key<<32 | org), ascending; pads sort last.
__device__ __forceinline__ unsigned long long bitonic64p(unsigned long long v, int lane) {
    for (int k = 2; k <= 64; k <<= 1) {
        for (int j = k >> 1; j > 0; j >>= 1) {
            unsigned long long pv = __shfl_xor(v, j, 64);
            bool takeMin = (((lane & j) == 0) == ((lane & k) == 0));
            unsigned long long lo = pv < v ? pv : v;
            unsigned long long hi = pv < v ? v : pv;
            v = takeMin ? lo : hi;
        }
    }
    return v;
}

// kA: coarse LDS histogram + ntri/mask/tiB outputs + flags
__global__ void kA_hist(const int* __restrict__ tets, const float* __restrict__ sdf,
                        unsigned* __restrict__ gHist, unsigned* __restrict__ flags,
                        float* __restrict__ out_ntri, float* __restrict__ out_mask,
                        unsigned char* __restrict__ tiB) {
    __shared__ unsigned h[NC];
    __shared__ unsigned bf[2];
    int tid = threadIdx.x;
    for (int i = tid; i < NC; i += 256) h[i] = 0;
    if (tid == 0) { bf[0] = 0; bf[1] = 0; }
    __syncthreads();
    bool anyInv = false, anyZ = false;
    for (int f = blockIdx.x * 256 + tid; f < NFF; f += NBLK1 * 256) {
        const int4 tv = ((const int4*)tets)[f];
        int v0 = tv.x, v1 = tv.y, v2 = tv.z, v3 = tv.w;
        int ti = tidx(sdf, v0, v1, v2, v3);
        tiB[f] = (unsigned char)ti;
        unsigned row = TROW[ti];
        bool has1 = (row & 7u) != 7u;
        bool has2 = ((row >> 9) & 7u) != 7u;
        out_ntri[f] = has2 ? 2.0f : (has1 ? 1.0f : 0.0f);
        ((float2*)out_mask)[f] = make_float2(has1 ? 1.0f : 0.0f, has2 ? 1.0f : 0.0f);
        if (!has1) { anyInv = true; continue; }
#define H_EDGE(A,B) { unsigned sk_ = skey_of(A, B); \
    if (sk_ == 0x80000000u) anyZ = true; \
    atomicAdd(&h[sk_ >> CSH], 1u); }
        H_EDGE(v0, v1) H_EDGE(v0, v2) H_EDGE(v0, v3)
        H_EDGE(v1, v2) H_EDGE(v1, v3) H_EDGE(v2, v3)
#undef H_EDGE
    }
    if (anyInv) atomicOr(&bf[0], 1u);
    if (anyZ) atomicOr(&bf[1], 1u);
    __syncthreads();
    for (int i = tid; i < NC; i += 256)
        gHist[(size_t)i * NBLK1 + blockIdx.x] = h[i];
    if (tid == 0) {
        if (bf[0]) atomicOr(&flags[0], 1u);
        if (bf[1]) atomicOr(&flags[1], 1u);
    }
}

// exclusive block scan (Hillis-Steele); bsums optional
__global__ void scan_block(const unsigned* __restrict__ in, unsigned* __restrict__ out,
                           unsigned* __restrict__ bsums, int n) {
    __shared__ unsigned s[1024];
    int tid = threadIdx.x;
    int g = blockIdx.x * 1024 + tid;
    unsigned v = (g < n) ? in[g] : 0u;
    s[tid] = v;
    __syncthreads();
    for (int off = 1; off < 1024; off <<= 1) {
        unsigned t = (tid >= off) ? s[tid - off] : 0u;
        __syncthreads();
        s[tid] += t;
        __syncthreads();
    }
    if (g < n) out[g] = s[tid] - v;
    if (tid == 1023 && bsums) bsums[blockIdx.x] = s[1023];
}

__global__ void scan_add(unsigned* __restrict__ out, const unsigned* __restrict__ ssums,
                         const unsigned* __restrict__ in, unsigned* __restrict__ total, int n) {
    int g = blockIdx.x * 1024 + threadIdx.x;
    if (g >= n) return;
    unsigned v = out[g] + ssums[g >> 10];
    out[g] = v;
    if (g == n - 1) *total = v + in[g];
}

// kB: scatter pairs into coarse-grouped staging via LDS cursors (ti from tiB)
__global__ void kB_scatter(const int* __restrict__ tets, const unsigned char* __restrict__ tiB,
                           const unsigned* __restrict__ gScan, uint2* __restrict__ staging) {
    __shared__ unsigned cur[NC];
    int tid = threadIdx.x;
    for (int i = tid; i < NC; i += 256)
        cur[i] = gScan[(size_t)i * NBLK1 + blockIdx.x];
    __syncthreads();
    for (int f = blockIdx.x * 256 + tid; f < NFF; f += NBLK1 * 256) {
        int ti = tiB[f];
        if (ti == 0 || ti == 15) continue;
        const int4 tv = ((const int4*)tets)[f];
        int v0 = tv.x, v1 = tv.y, v2 = tv.z, v3 = tv.w;
        unsigned base = (unsigned)f * 6u;
#define S_EDGE(A,B,E) { unsigned sk_ = skey_of(A, B); \
    unsigned p_ = atomicAdd(&cur[sk_ >> CSH], 1u); \
    staging[p_] = make_uint2(sk_, base + (E)); }
        S_EDGE(v0, v1, 0u) S_EDGE(v0, v2, 1u) S_EDGE(v0, v3, 2u)
        S_EDGE(v1, v2, 3u) S_EDGE(v1, v3, 4u) S_EDGE(v2, v3, 5u)
#undef S_EDGE
    }
}

// kC: per-coarse-bucket fine binning -> bPair + off1; then phase 2 computes
// dcnt per fine bin from the just-written (L2-hot) bins. NO writeback.
__global__ void kC_fine(const unsigned* __restrict__ gScan, const unsigned* __restrict__ totalE,
                        const uint2* __restrict__ staging, uint2* __restrict__ bPair,
                        unsigned* __restrict__ off1, unsigned* __restrict__ dcnt) {
    __shared__ unsigned fh[NF2];
    __shared__ unsigned fs[NF2];
    int c = blockIdx.x, tid = threadIdx.x;
    unsigned s = gScan[(size_t)c * NBLK1];
    unsigned e = (c < NC - 1) ? gScan[(size_t)(c + 1) * NBLK1] : *totalE;
    for (int i = tid; i < NF2; i += 256) fh[i] = 0;
    __syncthreads();
    for (unsigned i = s + tid; i < e; i += 256)
        atomicAdd(&fh[(staging[i].x >> BSH) & (NF2 - 1)], 1u);
    __syncthreads();
    if (tid == 0) {
        unsigned acc = 0;
        for (int i = 0; i < NF2; i++) { fs[i] = acc; acc += fh[i]; }
    }
    __syncthreads();
    for (int i = tid; i < NF2; i += 256) {
        unsigned v = s + fs[i];
        off1[(size_t)c * NF2 + i] = v;
        fh[i] = v;                       // running cursor
    }
    __syncthreads();
    for (unsigned i = s + tid; i < e; i += 256) {
        uint2 t = staging[i];
        unsigned pos = atomicAdd(&fh[(t.x >> BSH) & (NF2 - 1)], 1u);
        bPair[pos] = t;
    }
    __threadfence_block();
    __syncthreads();
    // phase 2: each wave computes dcnt for its 128 fine bins (bins are L2-hot)
    int w = tid >> 6, lane = tid & 63;
    for (int i = w * 128; i < w * 128 + 128; ++i) {
        unsigned start = s + fs[i];
        unsigned n = fh[i] - start;
        unsigned db = (unsigned)c * NF2 + (unsigned)i;
        if (n == 0u) { if (lane == 0) dcnt[db] = 0u; continue; }
        if (n <= 64u) {
            unsigned long long v = 0xFFFFFFFFFFFFFFFFull;
            if (lane < (int)n) {
                uint2 t = bPair[start + lane];
                v = ((unsigned long long)t.x << 32) | t.y;
            }
            v = bitonic64p(v, lane);
            unsigned key = (unsigned)(v >> 32);
            bool valid = (v != 0xFFFFFFFFFFFFFFFFull);
            unsigned prev = __shfl_up(key, 1, 64);
            bool rep = valid && (lane == 0 || key != prev);
            unsigned long long m = __ballot(rep);
            if (lane == 0) dcnt[db] = (unsigned)__popcll(m);
        } else {
            // astronomically rare: O(n^2) distinct count
            unsigned cnt = 0;
            for (unsigned q = lane; q < n; q += 64) {
                unsigned my = bPair[start + q].x;
                bool rep = true;
                for (unsigned j = 0; j < q; j++)
                    if (bPair[start + j].x == my) { rep = false; break; }
                cnt += rep ? 1u : 0u;
            }
#pragma unroll
            for (int o = 32; o > 0; o >>= 1) cnt += __shfl_down(cnt, o);
            if (lane == 0) dcnt[db] = cnt;
        }
    }
}

__device__ __forceinline__ void decode_key(unsigned sk, int* iua, int* iub) {
    int key = (int)(sk ^ 0x80000000u);
    long long kk = (long long)key;
    long long q = kk / 300000LL;
    long long r = kk - q * 300000LL;
    if (r < 0) { q -= 1; r += 300000LL; }
    int ua = (int)q;
    if (ua < 0) ua += NVV;
    *iua = ua;
    *iub = (int)r;
}

__device__ __forceinline__ void write_vert(unsigned sk, unsigned g,
                                           const float* __restrict__ pos,
                                           const float* __restrict__ sdf,
                                           float* __restrict__ out_verts,
                                           float* __restrict__ out_cross) {
    int ua, ub;
    decode_key(sk, &ua, &ub);
    float s0 = sdf[ua], s1 = sdf[ub];
    bool cr = (s0 > 0.0f) != (s1 > 0.0f);
    out_cross[g] = cr ? 1.0f : 0.0f;
    if (cr) {
        float denom = s0 - s1;
        float wa = -s1 / denom, wb = s0 / denom;
        out_verts[g * 3 + 0] = wa * pos[ua * 3 + 0] + wb * pos[ub * 3 + 0];
        out_verts[g * 3 + 1] = wa * pos[ua * 3 + 1] + wb * pos[ub * 3 + 1];
        out_verts[g * 3 + 2] = wa * pos[ua * 3 + 2] + wb * pos[ub * 3 + 2];
    }
}

// K3: wave-per-bucket ranks — packed register bitonic fast path (r12/r15)
__global__ void k3_rank(const float* __restrict__ pos, const float* __restrict__ sdf,
                        const unsigned* __restrict__ off1, const uint2* __restrict__ bPair,
                        const unsigned* __restrict__ base2, const unsigned* __restrict__ flags,
                        unsigned* __restrict__ idx_map,
                        float* __restrict__ out_verts, float* __restrict__ out_cross) {
    __shared__ unsigned keys[4][BCAP];
    __shared__ unsigned origs[4][BCAP];
    __shared__ unsigned char repf[4][BCAP];
    int w = threadIdx.x >> 6, lane = threadIdx.x & 63;
    unsigned b = blockIdx.x * 4u + (unsigned)w;
    unsigned s = off1[b], e = off1[b + 1];
    unsigned n = e - s;
    bool fast = (n <= 64u);
    bool lds = !fast && (n <= BCAP);
    bool needZ = (flags[0] != 0u) && (flags[1] == 0u);
    unsigned bb = base2[b];
    if (lds) for (unsigned i = lane; i < n; i += 64) {
        uint2 t = bPair[s + i];
        keys[w][i] = t.x;
        origs[w][i] = t.y;
    }
    __syncthreads();
    if (lds) for (unsigned i = lane; i < n; i += 64) {
        unsigned my = keys[w][i];
        unsigned char r = 1;
        for (unsigned j = 0; j < i; j++)
            if (keys[w][j] == my) { r = 0; break; }
        repf[w][i] = r;
    }
    __syncthreads();
    if (fast) {
        unsigned long long v = 0xFFFFFFFFFFFFFFFFull;
        if (lane < (int)n) {
            uint2 t = bPair[s + lane];
            v = ((unsigned long long)t.x << 32) | t.y;
        }
        v = bitonic64p(v, lane);
        unsigned key = (unsigned)(v >> 32);
        unsigned org = (unsigned)v;
        bool valid = (v != 0xFFFFFFFFFFFFFFFFull);
        unsigned prev = __shfl_up(key, 1, 64);
        bool rep = valid && (lane == 0 || key != prev);
        unsigned long long m = __ballot(rep);
        unsigned prefix = (unsigned)__popcll(m & ((1ull << lane) - 1ull));
        unsigned rank = prefix - ((valid && !rep) ? 1u : 0u);   // distinct rank
        unsigned g = bb + rank + ((needZ && key > 0x80000000u) ? 1u : 0u);
        if (valid) idx_map[org] = g;
        if (rep) write_vert(key, g, pos, sdf, out_verts, out_cross);
        return;
    }
    if (lds) {
        for (unsigned i = lane; i < n; i += 64) {
            unsigned my = keys[w][i];
            unsigned rank = 0;
            for (unsigned j = 0; j < n; j++)
                rank += (repf[w][j] && keys[w][j] < my) ? 1u : 0u;
            unsigned g = bb + rank + ((needZ && my > 0x80000000u) ? 1u : 0u);
            idx_map[origs[w][i]] = g;
            if (repf[w][i]) write_vert(my, g, pos, sdf, out_verts, out_cross);
        }
    } else {
        for (unsigned i = lane; i < n; i += 64) {
            unsigned my = bPair[s + i].x;
            bool isrep = true;
            for (unsigned j = 0; j < i; j++)
                if (bPair[s + j].x == my) { isrep = false; break; }
            unsigned rank = 0;
            for (unsigned j = 0; j < n; j++) {
                unsigned kj = bPair[s + j].x;
                if (kj < my) {
                    bool jr = true;
                    for (unsigned k = 0; k < j; k++)
                        if (bPair[s + k].x == kj) { jr = false; break; }
                    rank += jr ? 1u : 0u;
                }
            }
            unsigned g = bb + rank + ((needZ && my > 0x80000000u) ? 1u : 0u);
            idx_map[bPair[s + i].y] = g;
            if (isrep) write_vert(my, g, pos, sdf, out_verts, out_cross);
        }
    }
}

// K5: faces — ti from tiB, coalesced gather from idx_map, overwrite as float
__global__ void k5_faces(const unsigned char* __restrict__ tiB, void* faces_buf) {
    int f = blockIdx.x * 256 + threadIdx.x;
    if (f >= NFF) return;
    int ti = tiB[f];
    unsigned row = TROW[ti];
    bool has1 = (row & 7u) != 7u;
    bool has2 = ((row >> 9) & 7u) != 7u;
    float* of = (float*)faces_buf + (size_t)f * 6;
    if (!has1) {
        of[0] = -1.0f; of[1] = -1.0f; of[2] = -1.0f;
        of[3] = -1.0f; of[4] = -1.0f; of[5] = -1.0f;
        return;
    }
    const unsigned* im = (const unsigned*)faces_buf + (size_t)f * 6;
    float g0 = (float)im[0], g1 = (float)im[1], g2 = (float)im[2];
    float g3 = (float)im[3], g4 = (float)im[4], g5 = (float)im[5];
    unsigned l0 = row & 7u,         l1 = (row >> 3) & 7u,  l2 = (row >> 6) & 7u;
    unsigned l3 = (row >> 9) & 7u,  l4 = (row >> 12) & 7u, l5 = (row >> 15) & 7u;
#define SEL(L) ((L) == 0u ? g0 : (L) == 1u ? g1 : (L) == 2u ? g2 : \
                (L) == 3u ? g3 : (L) == 4u ? g4 : g5)
    float o0 = SEL(l0), o1 = SEL(l1), o2 = SEL(l2);
    float o3 = has2 ? SEL(l3) : -1.0f;
    float o4 = has2 ? SEL(l4) : -1.0f;
    float o5 = has2 ? SEL(l5) : -1.0f;
#undef SEL
    of[0] = o0; of[1] = o1; of[2] = o2;
    of[3] = o3; of[4] = o4; of[5] = o5;
}

// K6: uv atlas — runs LAST over the uvs region
__global__ void k6_uvs(float* __restrict__ out_uvs) {
    int c = blockIdx.x * 256 + threadIdx.x;
    if (c >= NGRID * NGRID) return;
    int i = c / NGRID, j = c - i * NGRID;
    const float inv = 1.0f / (float)NGRID;
    const float pad = 0.9f / (float)NGRID;
    float x = (float)j * inv;
    float y = (float)i * inv;
    float4* o = (float4*)(out_uvs + (size_t)c * 8);
    o[0] = make_float4(x, y, x + pad, y);
    o[1] = make_float4(x + pad, y + pad, x, y + pad);
}

// K7: uv_idx — runs LAST over the uv_idx region (covers tiB too)
__global__ void k7_uvidx(float* __restrict__ out_uvidx) {
    int f = blockIdx.x * 256 + threadIdx.x;
    if (f >= NFF) return;
    float base = (float)(4 * f);
    float2* uvi = (float2*)(out_uvidx + (size_t)f * 6);
    uvi[0] = make_float2(base, base + 1.0f);
    uvi[1] = make_float2(base + 2.0f, base);
    uvi[2] = make_float2(base + 2.0f, base + 3.0f);
}

extern "C" void kernel_launch(void* const* d_in, const int* in_sizes, int n_in,
                              void* d_out, int out_size, void* d_ws, size_t ws_size,
                              hipStream_t stream) {
    const float* pos = (const float*)d_in[0];
    const float* sdf = (const float*)d_in[1];
    const int* tets = (const int*)d_in[2];
    float* out = (float*)d_out;
    unsigned* u = (unsigned*)d_out;

    uint2*    bPair   = (uint2*)(u + S_PAIR);
    unsigned* gHist   = u + S_GH;
    unsigned* gScan   = u + S_GS;
    unsigned* dcnt    = u + S_GH;          // overlays gHist (dead after scan1)
    unsigned* base2   = u + S_GS;          // overlays gScan (dead after kC)
    unsigned* off1    = u + S_OFF1;
    unsigned* bsums   = u + S_BSUMS;
    unsigned* ssums   = u + S_SSUMS;
    unsigned* flags   = u + S_FLG;
    unsigned char* tiB = (unsigned char*)(u + S_TI);
    unsigned* idx_map = u + OFF_FACES;
    uint2*    staging = (uint2*)(u + OFF_VERTS);   // verts region until kC done

    hipMemsetAsync(flags, 0, 8 * 4, stream);
    hipMemsetAsync(out + OFF_CROSS, 0, (size_t)9000000 * 4, stream);

    dim3 blk(256);
    int gF = (NFF + 255) / 256;
    int gB = NB / 4;

    kA_hist<<<NBLK1, blk, 0, stream>>>(tets, sdf, gHist, flags,
                                       out + OFF_NTRI, out + OFF_MASK, tiB);

    scan_block<<<NHIST / 1024, 1024, 0, stream>>>(gHist, gScan, bsums, NHIST);
    scan_block<<<1, 1024, 0, stream>>>(bsums, ssums, nullptr, NHIST / 1024);
    scan_add<<<NHIST / 1024, 1024, 0, stream>>>(gScan, ssums, gHist, off1 + NB, NHIST);

    kB_scatter<<<NBLK1, blk, 0, stream>>>(tets, tiB, gScan, staging);
    // kC writes dcnt (overlaying gHist, dead) in its phase 2 — k2 is gone.
    kC_fine<<<NC, blk, 0, stream>>>(gScan, off1 + NB, staging, bPair, off1, dcnt);

    hipMemsetAsync(out + OFF_VERTS, 0, (size_t)27000000 * 4, stream);

    scan_block<<<NB / 1024, 1024, 0, stream>>>(dcnt, base2, bsums, NB);
    scan_block<<<1, 1024, 0, stream>>>(bsums, ssums, nullptr, NB / 1024);
    scan_add<<<NB / 1024, 1024, 0, stream>>>(base2, ssums, dcnt, base2 + NB, NB);

    k3_rank<<<gB, blk, 0, stream>>>(pos, sdf, off1, bPair, base2, flags,
                                    idx_map, out + OFF_VERTS, out + OFF_CROSS);
    k5_faces<<<gF, blk, 0, stream>>>(tiB, (void*)(out + OFF_FACES));

    int gC = (NGRID * NGRID + 255) / 256;
    k6_uvs<<<gC, blk, 0, stream>>>(out + OFF_UVS);
    k7_uvidx<<<gF, blk, 0, stream>>>(out + OFF_UVIDX);
}

// Round 17
// 627.396 us; speedup vs baseline: 1.1619x; 1.1619x over previous
//
#include <hip/hip_runtime.h>
#include <stdint.h>

#define NVV 300000
#define NFF 1500000
#define NE  9000000
#define NGRID 1225
#define NB   262144        // key-space buckets = 2^18 (fine)
#define BSH  14            // fine bucket = skey >> BSH
#define BCAP 256           // LDS bucket capacity per wave (k2/k3 fallback)
#define NC   512           // coarse bins
#define CSH  23            // coarse bin = skey >> CSH
#define NF2  512           // fine bins per coarse
#define NBLK1 2048         // blocks for kA/kB
#define NHIST (NC * NBLK1) // 1,048,576

// d_out layout (float32 element offsets)
#define OFF_VERTS 0
#define OFF_FACES 27000000
#define OFF_MASK  36000000
#define OFF_NTRI  39000000
#define OFF_CROSS 40500000
#define OFF_UVS   49500000
#define OFF_UVIDX 61505000

// ALL scratch lives in d_out; d_ws never used. Overlays (lifetime-disjoint):
//   dcnt  overlays gHist (dead after scan1's scan_add)
//   base2 overlays gScan (dead after kC)
#define S_PAIR  49500000u                  // bPair: 9M uint2 = 18M u32 -> 67,500,000
#define S_GH    67500000u                  // gHist: NHIST    [later: dcnt]
#define S_GS    (S_GH + NHIST)             // gScan: NHIST    [later: base2]
#define S_OFF1  (S_GS + NHIST)             // NB+1
#define S_BSUMS (S_OFF1 + NB + 1)          // 1024
#define S_SSUMS (S_BSUMS + 1024)           // 1024
#define S_FLG   (S_SSUMS + 1024)           // 8
#define S_TI    (S_FLG + 8)                // 375,000 u32 -> ends < 70,505,000
// staging: 9M uint2 in the verts region (memset after kC)
// idx_map: 9M u32 in the faces region (k3 -> k5)

#define ENC3(x) ((unsigned)(((x) < 0) ? 7 : (x)))
#define PACK6(a,b,c,d,e,f) (ENC3(a) | (ENC3(b)<<3) | (ENC3(c)<<6) | \
                            (ENC3(d)<<9) | (ENC3(e)<<12) | (ENC3(f)<<15))
__constant__ unsigned TROW[16] = {
    PACK6(-1,-1,-1,-1,-1,-1), PACK6(1,0,2,-1,-1,-1), PACK6(4,0,3,-1,-1,-1), PACK6(1,4,2,1,3,4),
    PACK6(3,1,5,-1,-1,-1),    PACK6(2,3,0,2,5,3),    PACK6(1,4,0,1,5,4),    PACK6(4,2,5,-1,-1,-1),
    PACK6(4,5,2,-1,-1,-1),    PACK6(4,1,0,4,5,1),    PACK6(3,2,0,3,5,2),    PACK6(1,3,5,-1,-1,-1),
    PACK6(4,1,2,4,3,1),       PACK6(3,0,4,-1,-1,-1), PACK6(2,0,1,-1,-1,-1), PACK6(-1,-1,-1,-1,-1,-1)};

__device__ __forceinline__ int tidx(const float* sdf, int v0, int v1, int v2, int v3) {
    int ti = 0;
    if (sdf[v0] > 0.0f) ti |= 1;
    if (sdf[v1] > 0.0f) ti |= 2;
    if (sdf[v2] > 0.0f) ti |= 4;
    if (sdf[v3] > 0.0f) ti |= 8;
    return ti;
}

__device__ __forceinline__ unsigned skey_of(int a, int b) {
    int ea = a < b ? a : b;
    int eb = a < b ? b : a;
    unsigned ukey = (unsigned)ea * 300000u + (unsigned)eb;   // wraps like int32
    return ukey ^ 0x80000000u;
}

// full-wave bitonic sort of packed (key<<32 | org), ascending; pads sort last.
__device__ __forceinline__ unsigned long long bitonic64p(unsigned long long v, int lane) {
    for (int k = 2; k <= 64; k <<= 1) {
        for (int j = k >> 1; j > 0; j >>= 1) {
            unsigned long long pv = __shfl_xor(v, j, 64);
            bool takeMin = (((lane & j) == 0) == ((lane & k) == 0));
            unsigned long long lo = pv < v ? pv : v;
            unsigned long long hi = pv < v ? v : pv;
            v = takeMin ? lo : hi;
        }
    }
    return v;
}

// kA: coarse LDS histogram + ntri/mask/tiB outputs + flags
__global__ void kA_hist(const int* __restrict__ tets, const float* __restrict__ sdf,
                        unsigned* __restrict__ gHist, unsigned* __restrict__ flags,
                        float* __restrict__ out_ntri, float* __restrict__ out_mask,
                        unsigned char* __restrict__ tiB) {
    __shared__ unsigned h[NC];
    __shared__ unsigned bf[2];
    int tid = threadIdx.x;
    for (int i = tid; i < NC; i += 256) h[i] = 0;
    if (tid == 0) { bf[0] = 0; bf[1] = 0; }
    __syncthreads();
    bool anyInv = false, anyZ = false;
    for (int f = blockIdx.x * 256 + tid; f < NFF; f += NBLK1 * 256) {
        const int4 tv = ((const int4*)tets)[f];
        int v0 = tv.x, v1 = tv.y, v2 = tv.z, v3 = tv.w;
        int ti = tidx(sdf, v0, v1, v2, v3);
        tiB[f] = (unsigned char)ti;
        unsigned row = TROW[ti];
        bool has1 = (row & 7u) != 7u;
        bool has2 = ((row >> 9) & 7u) != 7u;
        out_ntri[f] = has2 ? 2.0f : (has1 ? 1.0f : 0.0f);
        ((float2*)out_mask)[f] = make_float2(has1 ? 1.0f : 0.0f, has2 ? 1.0f : 0.0f);
        if (!has1) { anyInv = true; continue; }
#define H_EDGE(A,B) { unsigned sk_ = skey_of(A, B); \
    if (sk_ == 0x80000000u) anyZ = true; \
    atomicAdd(&h[sk_ >> CSH], 1u); }
        H_EDGE(v0, v1) H_EDGE(v0, v2) H_EDGE(v0, v3)
        H_EDGE(v1, v2) H_EDGE(v1, v3) H_EDGE(v2, v3)
#undef H_EDGE
    }
    if (anyInv) atomicOr(&bf[0], 1u);
    if (anyZ) atomicOr(&bf[1], 1u);
    __syncthreads();
    for (int i = tid; i < NC; i += 256)
        gHist[(size_t)i * NBLK1 + blockIdx.x] = h[i];
    if (tid == 0) {
        if (bf[0]) atomicOr(&flags[0], 1u);
        if (bf[1]) atomicOr(&flags[1], 1u);
    }
}

// exclusive block scan (Hillis-Steele); bsums optional
__global__ void scan_block(const unsigned* __restrict__ in, unsigned* __restrict__ out,
                           unsigned* __restrict__ bsums, int n) {
    __shared__ unsigned s[1024];
    int tid = threadIdx.x;
    int g = blockIdx.x * 1024 + tid;
    unsigned v = (g < n) ? in[g] : 0u;
    s[tid] = v;
    __syncthreads();
    for (int off = 1; off < 1024; off <<= 1) {
        unsigned t = (tid >= off) ? s[tid - off] : 0u;
        __syncthreads();
        s[tid] += t;
        __syncthreads();
    }
    if (g < n) out[g] = s[tid] - v;
    if (tid == 1023 && bsums) bsums[blockIdx.x] = s[1023];
}

__global__ void scan_add(unsigned* __restrict__ out, const unsigned* __restrict__ ssums,
                         const unsigned* __restrict__ in, unsigned* __restrict__ total, int n) {
    int g = blockIdx.x * 1024 + threadIdx.x;
    if (g >= n) return;
    unsigned v = out[g] + ssums[g >> 10];
    out[g] = v;
    if (g == n - 1) *total = v + in[g];
}

// kB: scatter pairs into coarse-grouped staging via LDS cursors (ti from tiB)
__global__ void kB_scatter(const int* __restrict__ tets, const unsigned char* __restrict__ tiB,
                           const unsigned* __restrict__ gScan, uint2* __restrict__ staging) {
    __shared__ unsigned cur[NC];
    int tid = threadIdx.x;
    for (int i = tid; i < NC; i += 256)
        cur[i] = gScan[(size_t)i * NBLK1 + blockIdx.x];
    __syncthreads();
    for (int f = blockIdx.x * 256 + tid; f < NFF; f += NBLK1 * 256) {
        int ti = tiB[f];
        if (ti == 0 || ti == 15) continue;
        const int4 tv = ((const int4*)tets)[f];
        int v0 = tv.x, v1 = tv.y, v2 = tv.z, v3 = tv.w;
        unsigned base = (unsigned)f * 6u;
#define S_EDGE(A,B,E) { unsigned sk_ = skey_of(A, B); \
    unsigned p_ = atomicAdd(&cur[sk_ >> CSH], 1u); \
    staging[p_] = make_uint2(sk_, base + (E)); }
        S_EDGE(v0, v1, 0u) S_EDGE(v0, v2, 1u) S_EDGE(v0, v3, 2u)
        S_EDGE(v1, v2, 3u) S_EDGE(v1, v3, 4u) S_EDGE(v2, v3, 5u)
#undef S_EDGE
    }
}

// kC: per-coarse-bucket fine binning -> bPair + off1
__global__ void kC_fine(const unsigned* __restrict__ gScan, const unsigned* __restrict__ totalE,
                        const uint2* __restrict__ staging, uint2* __restrict__ bPair,
                        unsigned* __restrict__ off1) {
    __shared__ unsigned fh[NF2];
    __shared__ unsigned fs[NF2];
    int c = blockIdx.x, tid = threadIdx.x;
    unsigned s = gScan[(size_t)c * NBLK1];
    unsigned e = (c < NC - 1) ? gScan[(size_t)(c + 1) * NBLK1] : *totalE;
    for (int i = tid; i < NF2; i += 256) fh[i] = 0;
    __syncthreads();
    for (unsigned i = s + tid; i < e; i += 256)
        atomicAdd(&fh[(staging[i].x >> BSH) & (NF2 - 1)], 1u);
    __syncthreads();
    if (tid == 0) {
        unsigned acc = 0;
        for (int i = 0; i < NF2; i++) { fs[i] = acc; acc += fh[i]; }
    }
    __syncthreads();
    for (int i = tid; i < NF2; i += 256) {
        unsigned v = s + fs[i];
        off1[(size_t)c * NF2 + i] = v;
        fh[i] = v;
    }
    __syncthreads();
    for (unsigned i = s + tid; i < e; i += 256) {
        uint2 t = staging[i];
        unsigned pos = atomicAdd(&fh[(t.x >> BSH) & (NF2 - 1)], 1u);
        bPair[pos] = t;
    }
}

// K2: wave-per-bucket distinct count — packed register bitonic fast path
__global__ void k2_count(const unsigned* __restrict__ off1,
                         const uint2* __restrict__ bPair,
                         unsigned* __restrict__ dcnt) {
    __shared__ unsigned keys[4][BCAP];
    int w = threadIdx.x >> 6, lane = threadIdx.x & 63;
    unsigned b = blockIdx.x * 4u + (unsigned)w;
    unsigned s = off1[b], e = off1[b + 1];
    unsigned n = e - s;
    bool fast = (n <= 64u);
    bool lds = !fast && (n <= BCAP);
    if (lds) for (unsigned i = lane; i < n; i += 64) keys[w][i] = bPair[s + i].x;
    __syncthreads();
    if (fast) {
        unsigned long long v = 0xFFFFFFFFFFFFFFFFull;
        if (lane < (int)n) {
            uint2 t = bPair[s + lane];
            v = ((unsigned long long)t.x << 32) | t.y;
        }
        v = bitonic64p(v, lane);
        unsigned key = (unsigned)(v >> 32);
        bool valid = (v != 0xFFFFFFFFFFFFFFFFull);
        unsigned prev = __shfl_up(key, 1, 64);
        bool rep = valid && (lane == 0 || key != prev);
        unsigned long long m = __ballot(rep);
        if (lane == 0) dcnt[b] = (unsigned)__popcll(m);
        return;
    }
    unsigned cnt = 0;
    if (lds) {
        for (unsigned i = lane; i < n; i += 64) {
            unsigned my = keys[w][i];
            bool rep = true;
            for (unsigned j = 0; j < i; j++)
                if (keys[w][j] == my) { rep = false; break; }
            cnt += rep ? 1u : 0u;
        }
    } else {
        for (unsigned i = lane; i < n; i += 64) {
            unsigned my = bPair[s + i].x;
            bool rep = true;
            for (unsigned j = 0; j < i; j++)
                if (bPair[s + j].x == my) { rep = false; break; }
            cnt += rep ? 1u : 0u;
        }
    }
#pragma unroll
    for (int o = 32; o > 0; o >>= 1) cnt += __shfl_down(cnt, o);
    if (lane == 0) dcnt[b] = cnt;
}

__device__ __forceinline__ void decode_key(unsigned sk, int* iua, int* iub) {
    int key = (int)(sk ^ 0x80000000u);
    long long kk = (long long)key;
    long long q = kk / 300000LL;
    long long r = kk - q * 300000LL;
    if (r < 0) { q -= 1; r += 300000LL; }
    int ua = (int)q;
    if (ua < 0) ua += NVV;
    *iua = ua;
    *iub = (int)r;
}

__device__ __forceinline__ void write_vert(unsigned sk, unsigned g,
                                           const float* __restrict__ pos,
                                           const float* __restrict__ sdf,
                                           float* __restrict__ out_verts,
                                           float* __restrict__ out_cross) {
    int ua, ub;
    decode_key(sk, &ua, &ub);
    float s0 = sdf[ua], s1 = sdf[ub];
    bool cr = (s0 > 0.0f) != (s1 > 0.0f);
    out_cross[g] = cr ? 1.0f : 0.0f;
    if (cr) {
        float denom = s0 - s1;
        float wa = -s1 / denom, wb = s0 / denom;
        out_verts[g * 3 + 0] = wa * pos[ua * 3 + 0] + wb * pos[ub * 3 + 0];
        out_verts[g * 3 + 1] = wa * pos[ua * 3 + 1] + wb * pos[ub * 3 + 1];
        out_verts[g * 3 + 2] = wa * pos[ua * 3 + 2] + wb * pos[ub * 3 + 2];
    }
}

// K3: wave-per-bucket ranks — packed register bitonic fast path (r12/r15)
__global__ void k3_rank(const float* __restrict__ pos, const float* __restrict__ sdf,
                        const unsigned* __restrict__ off1, const uint2* __restrict__ bPair,
                        const unsigned* __restrict__ base2, const unsigned* __restrict__ flags,
                        unsigned* __restrict__ idx_map,
                        float* __restrict__ out_verts, float* __restrict__ out_cross) {
    __shared__ unsigned keys[4][BCAP];
    __shared__ unsigned origs[4][BCAP];
    __shared__ unsigned char repf[4][BCAP];
    int w = threadIdx.x >> 6, lane = threadIdx.x & 63;
    unsigned b = blockIdx.x * 4u + (unsigned)w;
    unsigned s = off1[b], e = off1[b + 1];
    unsigned n = e - s;
    bool fast = (n <= 64u);
    bool lds = !fast && (n <= BCAP);
    bool needZ = (flags[0] != 0u) && (flags[1] == 0u);
    unsigned bb = base2[b];
    if (lds) for (unsigned i = lane; i < n; i += 64) {
        uint2 t = bPair[s + i];
        keys[w][i] = t.x;
        origs[w][i] = t.y;
    }
    __syncthreads();
    if (lds) for (unsigned i = lane; i < n; i += 64) {
        unsigned my = keys[w][i];
        unsigned char r = 1;
        for (unsigned j = 0; j < i; j++)
            if (keys[w][j] == my) { r = 0; break; }
        repf[w][i] = r;
    }
    __syncthreads();
    if (fast) {
        unsigned long long v = 0xFFFFFFFFFFFFFFFFull;
        if (lane < (int)n) {
            uint2 t = bPair[s + lane];
            v = ((unsigned long long)t.x << 32) | t.y;
        }
        v = bitonic64p(v, lane);
        unsigned key = (unsigned)(v >> 32);
        unsigned org = (unsigned)v;
        bool valid = (v != 0xFFFFFFFFFFFFFFFFull);
        unsigned prev = __shfl_up(key, 1, 64);
        bool rep = valid && (lane == 0 || key != prev);
        unsigned long long m = __ballot(rep);
        unsigned prefix = (unsigned)__popcll(m & ((1ull << lane) - 1ull));
        unsigned rank = prefix - ((valid && !rep) ? 1u : 0u);   // distinct rank
        unsigned g = bb + rank + ((needZ && key > 0x80000000u) ? 1u : 0u);
        if (valid) idx_map[org] = g;
        if (rep) write_vert(key, g, pos, sdf, out_verts, out_cross);
        return;
    }
    if (lds) {
        for (unsigned i = lane; i < n; i += 64) {
            unsigned my = keys[w][i];
            unsigned rank = 0;
            for (unsigned j = 0; j < n; j++)
                rank += (repf[w][j] && keys[w][j] < my) ? 1u : 0u;
            unsigned g = bb + rank + ((needZ && my > 0x80000000u) ? 1u : 0u);
            idx_map[origs[w][i]] = g;
            if (repf[w][i]) write_vert(my, g, pos, sdf, out_verts, out_cross);
        }
    } else {
        for (unsigned i = lane; i < n; i += 64) {
            unsigned my = bPair[s + i].x;
            bool isrep = true;
            for (unsigned j = 0; j < i; j++)
                if (bPair[s + j].x == my) { isrep = false; break; }
            unsigned rank = 0;
            for (unsigned j = 0; j < n; j++) {
                unsigned kj = bPair[s + j].x;
                if (kj < my) {
                    bool jr = true;
                    for (unsigned k = 0; k < j; k++)
                        if (bPair[s + k].x == kj) { jr = false; break; }
                    rank += jr ? 1u : 0u;
                }
            }
            unsigned g = bb + rank + ((needZ && my > 0x80000000u) ? 1u : 0u);
            idx_map[bPair[s + i].y] = g;
            if (isrep) write_vert(my, g, pos, sdf, out_verts, out_cross);
        }
    }
}

// K5: faces — ti from tiB, coalesced gather from idx_map, overwrite as float
__global__ void k5_faces(const unsigned char* __restrict__ tiB, void* faces_buf) {
    int f = blockIdx.x * 256 + threadIdx.x;
    if (f >= NFF) return;
    int ti = tiB[f];
    unsigned row = TROW[ti];
    bool has1 = (row & 7u) != 7u;
    bool has2 = ((row >> 9) & 7u) != 7u;
    float* of = (float*)faces_buf + (size_t)f * 6;
    if (!has1) {
        of[0] = -1.0f; of[1] = -1.0f; of[2] = -1.0f;
        of[3] = -1.0f; of[4] = -1.0f; of[5] = -1.0f;
        return;
    }
    const unsigned* im = (const unsigned*)faces_buf + (size_t)f * 6;
    float g0 = (float)im[0], g1 = (float)im[1], g2 = (float)im[2];
    float g3 = (float)im[3], g4 = (float)im[4], g5 = (float)im[5];
    unsigned l0 = row & 7u,         l1 = (row >> 3) & 7u,  l2 = (row >> 6) & 7u;
    unsigned l3 = (row >> 9) & 7u,  l4 = (row >> 12) & 7u, l5 = (row >> 15) & 7u;
#define SEL(L) ((L) == 0u ? g0 : (L) == 1u ? g1 : (L) == 2u ? g2 : \
                (L) == 3u ? g3 : (L) == 4u ? g4 : g5)
    float o0 = SEL(l0), o1 = SEL(l1), o2 = SEL(l2);
    float o3 = has2 ? SEL(l3) : -1.0f;
    float o4 = has2 ? SEL(l4) : -1.0f;
    float o5 = has2 ? SEL(l5) : -1.0f;
#undef SEL
    of[0] = o0; of[1] = o1; of[2] = o2;
    of[3] = o3; of[4] = o4; of[5] = o5;
}

// K6: uv atlas — runs LAST over the uvs region
__global__ void k6_uvs(float* __restrict__ out_uvs) {
    int c = blockIdx.x * 256 + threadIdx.x;
    if (c >= NGRID * NGRID) return;
    int i = c / NGRID, j = c - i * NGRID;
    const float inv = 1.0f / (float)NGRID;
    const float pad = 0.9f / (float)NGRID;
    float x = (float)j * inv;
    float y = (float)i * inv;
    float4* o = (float4*)(out_uvs + (size_t)c * 8);
    o[0] = make_float4(x, y, x + pad, y);
    o[1] = make_float4(x + pad, y + pad, x, y + pad);
}

// K7: uv_idx — runs LAST over the uv_idx region (covers tiB too)
__global__ void k7_uvidx(float* __restrict__ out_uvidx) {
    int f = blockIdx.x * 256 + threadIdx.x;
    if (f >= NFF) return;
    float base = (float)(4 * f);
    float2* uvi = (float2*)(out_uvidx + (size_t)f * 6);
    uvi[0] = make_float2(base, base + 1.0f);
    uvi[1] = make_float2(base + 2.0f, base);
    uvi[2] = make_float2(base + 2.0f, base + 3.0f);
}

extern "C" void kernel_launch(void* const* d_in, const int* in_sizes, int n_in,
                              void* d_out, int out_size, void* d_ws, size_t ws_size,
                              hipStream_t stream) {
    const float* pos = (const float*)d_in[0];
    const float* sdf = (const float*)d_in[1];
    const int* tets = (const int*)d_in[2];
    float* out = (float*)d_out;
    unsigned* u = (unsigned*)d_out;

    uint2*    bPair   = (uint2*)(u + S_PAIR);
    unsigned* gHist   = u + S_GH;
    unsigned* gScan   = u + S_GS;
    unsigned* dcnt    = u + S_GH;          // overlays gHist (dead after scan1)
    unsigned* base2   = u + S_GS;          // overlays gScan (dead after kC)
    unsigned* off1    = u + S_OFF1;
    unsigned* bsums   = u + S_BSUMS;
    unsigned* ssums   = u + S_SSUMS;
    unsigned* flags   = u + S_FLG;
    unsigned char* tiB = (unsigned char*)(u + S_TI);
    unsigned* idx_map = u + OFF_FACES;
    uint2*    staging = (uint2*)(u + OFF_VERTS);   // verts region until kC done

    hipMemsetAsync(flags, 0, 8 * 4, stream);
    hipMemsetAsync(out + OFF_CROSS, 0, (size_t)9000000 * 4, stream);

    dim3 blk(256);
    int gF = (NFF + 255) / 256;
    int gB = NB / 4;

    kA_hist<<<NBLK1, blk, 0, stream>>>(tets, sdf, gHist, flags,
                                       out + OFF_NTRI, out + OFF_MASK, tiB);

    scan_block<<<NHIST / 1024, 1024, 0, stream>>>(gHist, gScan, bsums, NHIST);
    scan_block<<<1, 1024, 0, stream>>>(bsums, ssums, nullptr, NHIST / 1024);
    scan_add<<<NHIST / 1024, 1024, 0, stream>>>(gScan, ssums, gHist, off1 + NB, NHIST);

    kB_scatter<<<NBLK1, blk, 0, stream>>>(tets, tiB, gScan, staging);
    kC_fine<<<NC, blk, 0, stream>>>(gScan, off1 + NB, staging, bPair, off1);

    hipMemsetAsync(out + OFF_VERTS, 0, (size_t)27000000 * 4, stream);

    k2_count<<<gB, blk, 0, stream>>>(off1, bPair, dcnt);

    scan_block<<<NB / 1024, 1024, 0, stream>>>(dcnt, base2, bsums, NB);
    scan_block<<<1, 1024, 0, stream>>>(bsums, ssums, nullptr, NB / 1024);
    scan_add<<<NB / 1024, 1024, 0, stream>>>(base2, ssums, dcnt, base2 + NB, NB);

    k3_rank<<<gB, blk, 0, stream>>>(pos, sdf, off1, bPair, base2, flags,
                                    idx_map, out + OFF_VERTS, out + OFF_CROSS);
    k5_faces<<<gF, blk, 0, stream>>>(tiB, (void*)(out + OFF_FACES));

    int gC = (NGRID * NGRID + 255) / 256;
    k6_uvs<<<gC, blk, 0, stream>>>(out + OFF_UVS);
    k7_uvidx<<<gF, blk, 0, stream>>>(out + OFF_UVIDX);
}